// Round 9
// baseline (296.615 us; speedup 1.0000x reference)
//
#include <hip/hip_runtime.h>
#include <hip/hip_cooperative_groups.h>
#include <math.h>

namespace cg = cooperative_groups;

#define S_LEN 1024
#define EPS 1e-6f

typedef __attribute__((ext_vector_type(8)))  short bf16x8;
typedef __attribute__((ext_vector_type(16))) float float16v;

// Workspace layout (bytes):
//   kcnt2  : int  [32*32*64]      @ 0          (262144)  per (bh, seg, dim)
//   qcnt2  : int  [32*32*64]      @ 262144     (262144)
//   klist2 : ushort [2048*1024]   @ 524288     (4194304) [(bh,dim)][seg*32+pos]
//   qpair  : uint [2048*1024]     @ 4718592    (8388608) packed (w_hi22 | s_10)
// No memsets needed: counts fully overwritten each call; slots beyond count
// never read; d_out zeroed in phase 1 before any atomics.

__device__ __forceinline__ void wave_argmax(float& bv, int& bi) {
    #pragma unroll
    for (int off = 1; off < 64; off <<= 1) {
        float ov = __shfl_xor(bv, off, 64);
        int   oi = __shfl_xor(bi, off, 64);
        if (ov > bv || (ov == bv && oi < bi)) { bv = ov; bi = oi; }
    }
}

__device__ __forceinline__ unsigned short f2bf(float f) {
    unsigned int u = __float_as_uint(f);
    unsigned int r = (u + 0x7fffu + ((u >> 16) & 1u)) >> 16;
    return (unsigned short)r;
}

__device__ __forceinline__ bf16x8 pack8(float4 a, float4 b) {
    bf16x8 r;
    r[0] = (short)f2bf(a.x); r[1] = (short)f2bf(a.y);
    r[2] = (short)f2bf(a.z); r[3] = (short)f2bf(a.w);
    r[4] = (short)f2bf(b.x); r[5] = (short)f2bf(b.y);
    r[6] = (short)f2bf(b.z); r[7] = (short)f2bf(b.w);
    return r;
}

// Single cooperative kernel, grid-size-agnostic (loops stride by gridDim).
// Phase 1: per (bh,seg) segment -- key argmax (6-shuffle) + query top-16
// (rank counting) into segmented lists, zero d_out slice. grid.sync().
// Phase 2: per (bh,bank) task (NO chunk split -- build M once) -- build
// M(64x64)->bf16 + z fp32, then 64-query batches: bf16 Q staging with fp64
// den, 4 MFMAs/wave, O transpose via LDS, pipelined coalesced atomic flush.
__global__ __launch_bounds__(256) void k_fused(const float* __restrict__ keys,
                                               const float* __restrict__ values,
                                               const float* __restrict__ queries,
                                               int* __restrict__ kcnt2,
                                               unsigned short* __restrict__ klist2,
                                               int* __restrict__ qcnt2,
                                               unsigned* __restrict__ qpair,
                                               float* __restrict__ out) {
    const int t    = threadIdx.x;
    const int lane = t & 63;
    const int grp  = t >> 6;

    __shared__ alignas(16) unsigned short M_bf[64 * 64];   // 8 KB
    __shared__ alignas(16) unsigned short Q_bf[64 * 64];   // 8 KB
    __shared__ alignas(16) float Ou[64 * 66];              // 16.5 KB (O / staging / hist)
    __shared__ unsigned short s_match[1024];               // 2 KB
    __shared__ unsigned q_ent[256];                        // 1 KB chunked entries
    __shared__ int    koffs_s[33], qoffs_s[33];
    __shared__ float  z_s[64];
    __shared__ double den_s[64];
    __shared__ float  w_s[2][64];
    __shared__ int    sq_s[2][64];
    // total ~38.5 KB -> 4 blocks/CU

    // ================= phase 1: build segmented lists =================
    int* khist = (int*)Ou;             // alias build/O buffer (free in phase 1)
    int* qhist = khist + 64;
    for (int sb = blockIdx.x; sb < 1024; sb += gridDim.x) {
        const int bh = sb >> 5, blk = sb & 31;
        __syncthreads();               // hist reuse across sb iterations
        if (t < 64) { khist[t] = 0; qhist[t] = 0; }
        __syncthreads();

        const int s0 = blk * 32 + grp * 8;
        float kv[8], qv[8];
        #pragma unroll
        for (int i = 0; i < 8; ++i) {  // all loads up-front (ILP)
            kv[i] = keys   [((size_t)bh * 1024 + s0 + i) * 64 + lane];
            qv[i] = queries[((size_t)bh * 1024 + s0 + i) * 64 + lane];
        }

        // keys: first-occurrence argmax |k| (shuffle chain -- measured faster
        // than rank counting here, R7 vs R8)
        #pragma unroll
        for (int i = 0; i < 8; ++i) {
            float bv = fabsf(kv[i]); int bi = lane;
            wave_argmax(bv, bi);
            if (lane == 0) {
                int pos = atomicAdd(&khist[bi], 1);
                klist2[((size_t)bh * 64 + bi) * 1024 + blk * 32 + pos] =
                    (unsigned short)(s0 + i);
            }
        }

        // queries: exact duplicated-top-16 by rank counting
        #pragma unroll
        for (int i = 0; i < 8; ++i) {
            unsigned ud = __float_as_uint(qv[i]) & 0x7fffffffu;
            int gt = 0, eq = 0, eql = 0;
            #pragma unroll
            for (int k = 0; k < 64; ++k) {
                unsigned ui = (unsigned)__builtin_amdgcn_readlane((int)ud, k);
                gt  += (ui > ud) ? 1 : 0;
                eq  += (ui == ud) ? 1 : 0;
                eql += (ui == ud && k < lane) ? 1 : 0;
            }
            int pos_low  = 2 * gt + eql;
            int pos_high = pos_low + eq;       // eq includes self
            int copies   = (pos_low < 16 ? 1 : 0) + (pos_high < 16 ? 1 : 0);
            float e  = expf(__uint_as_float(ud));
            float ce = (float)copies * e;
            #pragma unroll
            for (int off = 1; off < 64; off <<= 1) ce += __shfl_xor(ce, off, 64);
            if (pos_low < 16) {
                int pos = atomicAdd(&qhist[lane], 1);
                unsigned wb = __float_as_uint(e / ce) & 0xFFFFFC00u;
                qpair[((size_t)bh * 64 + lane) * 1024 + blk * 32 + pos] =
                    wb | (unsigned)(s0 + i);
            }
        }
        __syncthreads();
        if (t < 64) {
            kcnt2[(bh * 32 + blk) * 64 + t] = khist[t];
            qcnt2[(bh * 32 + blk) * 64 + t] = qhist[t];
        }
        // zero this block's d_out slice (8 KB) -- replaces hipMemsetAsync
        float4 zz = {0.f, 0.f, 0.f, 0.f};
        float4* po = (float4*)(out + (size_t)sb * 2048);
        po[t] = zz; po[t + 256] = zz;
    }

    cg::this_grid().sync();            // lists + zeros visible device-wide

    // ================= phase 2: build M and process queries =================
    const int dvh = grp >> 1, jh = grp & 1;    // wave's 32x32 MFMA tile
    for (int task = blockIdx.x; task < 2048; task += gridDim.x) {
        const int bh = task >> 6, bank = task & 63;
        __syncthreads();               // prev task's LDS reads complete

        // wave 0: both 32-entry prefix scans (lanes 0-31 keys, 32-63 queries)
        if (t < 64) {
            int i = t & 31;
            int c = (t < 32) ? kcnt2[(bh * 32 + i) * 64 + bank]
                             : qcnt2[(bh * 32 + i) * 64 + bank];
            #pragma unroll
            for (int off = 1; off < 32; off <<= 1) {
                int o = __shfl(c, t - off, 64);
                if (i >= off) c += o;
            }
            if (t < 32) { if (i == 0) koffs_s[0] = 0; koffs_s[i + 1] = c; }
            else        { if (i == 0) qoffs_s[0] = 0; qoffs_s[i + 1] = c; }
        }
        __syncthreads();
        const int nm = koffs_s[32];
        const int nq = qoffs_s[32];
        if (nm == 0 || nq == 0) continue;      // uniform skip

        // gather key list via segment search (LDS offs, broadcast reads)
        for (int idx = t; idx < nm; idx += 256) {
            int seg = 0;
            #pragma unroll
            for (int i = 1; i < 32; ++i) if (idx >= koffs_s[i]) seg = i;
            s_match[idx] = klist2[(size_t)(bh * 64 + bank) * 1024 + seg * 32 +
                                  (idx - koffs_s[seg])];
        }
        __syncthreads();

        // ---- build M[dv][dk] = sum v[dv]*k[dk], z[dk] = sum k[dk] ----
        float acc[16];
        #pragma unroll
        for (int m = 0; m < 16; ++m) acc[m] = 0.f;
        float zacc = 0.f;
        const float* kb = keys   + (size_t)bh * S_LEN * 64;
        const float* vb = values + (size_t)bh * S_LEN * 64;
        for (int base = 0, it = 0; base < nm; base += 8, ++it) {
            float* kst = Ou + (it & 1) * 1024; // [8][64] ping-pong
            float* vst = kst + 512;
            #pragma unroll
            for (int rr = 0; rr < 2; ++rr) {
                int row = grp + rr * 4;
                if (base + row < nm) {
                    int s = s_match[base + row];
                    kst[row * 64 + lane] = kb[(size_t)s * 64 + lane];
                    vst[row * 64 + lane] = vb[(size_t)s * 64 + lane];
                }
            }
            __syncthreads();           // 1 barrier/iter (double-buffered)
            int lim = min(8, nm - base);
            for (int jj = 0; jj < lim; ++jj) {
                float kv2 = kst[jj * 64 + lane];       // dk = lane
                #pragma unroll
                for (int m = 0; m < 16; ++m)           // dv = grp*16+m
                    acc[m] += vst[jj * 64 + grp * 16 + m] * kv2;
            }
            if (t < 64)
                for (int jj = 0; jj < lim; ++jj) zacc += kst[jj * 64 + t];
        }
        // write M as bf16, row-major [dv][dk], 16B-chunk XOR swizzle
        #pragma unroll
        for (int m = 0; m < 16; ++m) {
            int dv = grp * 16 + m;
            M_bf[dv * 64 + (((lane >> 3) ^ (dv & 7)) << 3) + (lane & 7)] = f2bf(acc[m]);
        }
        if (t < 64) z_s[t] = zacc;
        // (visibility covered by the first chunk-gather barrier below)

        // ---- query loop: pipelined, 2 barriers/batch + 1 per 256-chunk ----
        const float* qb = queries + (size_t)bh * S_LEN * 64;
        float*       ob = out     + (size_t)bh * S_LEN * 64;
        int prev_nb = 0;
        for (int qbase = 0, batch = 0; qbase < nq; qbase += 64, ++batch) {
            const int nb  = min(64, nq - qbase);
            const int cur = batch & 1;

            if ((qbase & 255) == 0) {  // gather next 256 entries into q_ent
                if (qbase + t < nq) {
                    int jg = qbase + t;
                    int seg = 0;
                    #pragma unroll
                    for (int i = 1; i < 32; ++i) if (jg >= qoffs_s[i]) seg = i;
                    q_ent[t] = qpair[(size_t)(bh * 64 + bank) * 1024 + seg * 32 +
                                     (jg - qoffs_s[seg])];
                }
                __syncthreads();       // q_ent (and M_bf/z_s on first iter)
            }

            // phase S: flush previous batch ...
            if (batch > 0) {
                #pragma unroll
                for (int jj = 0; jj < 16; ++jj) {
                    int j = grp * 16 + jj;
                    if (j < prev_nb) {
                        float v = Ou[j * 66 + lane];
                        unsafeAtomicAdd(&ob[(size_t)sq_s[1 - cur][j] * 64 + lane], v);
                    }
                }
            }
            // ... and stage current: thread -> (j = t>>2, slice c4 = t&3)
            {
                int j = t >> 2, c4 = t & 3;
                bf16x8 p0 = {}, p1 = {};
                double d = 0.0;
                if (j < nb) {
                    unsigned e = q_ent[(qbase & 255) + j];
                    int s = (int)(e & 1023u);
                    if ((t & 3) == 0) {
                        sq_s[cur][j] = s;
                        w_s[cur][j]  = __uint_as_float(e & 0xFFFFFC00u);
                    }
                    const float4* src = (const float4*)(qb + (size_t)s * 64 + c4 * 16);
                    float4 f0 = src[0], f1 = src[1], f2 = src[2], f3 = src[3];
                    p0 = pack8(f0, f1);
                    p1 = pack8(f2, f3);
                    const float4* zz4 = (const float4*)&z_s[c4 * 16];
                    float4 z0 = zz4[0], z1 = zz4[1], z2 = zz4[2], z3 = zz4[3];
                    d  = (double)z0.x * f0.x + (double)z0.y * f0.y + (double)z0.z * f0.z + (double)z0.w * f0.w;
                    d += (double)z1.x * f1.x + (double)z1.y * f1.y + (double)z1.z * f1.z + (double)z1.w * f1.w;
                    d += (double)z2.x * f2.x + (double)z2.y * f2.y + (double)z2.z * f2.z + (double)z2.w * f2.w;
                    d += (double)z3.x * f3.x + (double)z3.y * f3.y + (double)z3.z * f3.z + (double)z3.w * f3.w;
                }
                int c0 = c4 * 2;
                *(bf16x8*)&Q_bf[j * 64 + ((c0 ^ (j & 7)) << 3)]       = p0;
                *(bf16x8*)&Q_bf[j * 64 + (((c0 + 1) ^ (j & 7)) << 3)] = p1;
                d += __shfl_xor(d, 1, 64);
                d += __shfl_xor(d, 2, 64);
                if ((t & 3) == 0) den_s[j] = d;
            }
            __syncthreads();           // (C) staged; prev Ou reads complete

            // MFMA: O[dv][j] = sum_dk M[dv][dk] * Q[j][dk]
            float16v C;
            #pragma unroll
            for (int i = 0; i < 16; ++i) C[i] = 0.f;
            const int am = dvh * 32 + (lane & 31);
            const int bn = jh  * 32 + (lane & 31);
            #pragma unroll
            for (int ks = 0; ks < 4; ++ks) {
                int ch = ks * 2 + (lane >> 5);
                bf16x8 af = *(const bf16x8*)&M_bf[am * 64 + ((ch ^ (am & 7)) << 3)];
                bf16x8 bf = *(const bf16x8*)&Q_bf[bn * 64 + ((ch ^ (bn & 7)) << 3)];
                C = __builtin_amdgcn_mfma_f32_32x32x16_bf16(af, bf, C, 0, 0, 0);
            }
            // epilogue: scale by w/den, write O[j][dv] (stride 66)
            {
                double den = den_s[bn];
                float  w   = w_s[cur][bn];
                float rinv = (float)((double)w / (den + (double)EPS));
                #pragma unroll
                for (int r = 0; r < 16; ++r) {
                    int dv = dvh * 32 + (r & 3) + 8 * (r >> 2) + 4 * (lane >> 5);
                    Ou[bn * 66 + dv] = C[r] * rinv;
                }
            }
            __syncthreads();           // (D) O ready; Q_bf reads complete
            prev_nb = nb;
        }
        // final flush
        {
            const int cur = (((nq + 63) >> 6) - 1) & 1;
            #pragma unroll
            for (int jj = 0; jj < 16; ++jj) {
                int j = grp * 16 + jj;
                if (j < prev_nb) {
                    float v = Ou[j * 66 + lane];
                    unsafeAtomicAdd(&ob[(size_t)sq_s[cur][j] * 64 + lane], v);
                }
            }
        }
    }
}

extern "C" void kernel_launch(void* const* d_in, const int* in_sizes, int n_in,
                              void* d_out, int out_size, void* d_ws, size_t ws_size,
                              hipStream_t stream) {
    const float* keys    = (const float*)d_in[0];
    const float* values  = (const float*)d_in[1];
    const float* queries = (const float*)d_in[2];
    char* ws = (char*)d_ws;
    int*            kcnt2  = (int*)(ws);
    int*            qcnt2  = (int*)(ws + 262144);
    unsigned short* klist2 = (unsigned short*)(ws + 524288);
    unsigned*       qpair  = (unsigned*)(ws + 4718592);
    float*          outp   = (float*)d_out;

    int nbpc = 0;                      // blocks per CU (deterministic query)
    hipOccupancyMaxActiveBlocksPerMultiprocessor(&nbpc, k_fused, 256, 0);
    if (nbpc < 1) nbpc = 1;
    int grid = nbpc * 256;             // MI355X: 256 CUs
    if (grid > 1024) grid = 1024;      // 1024 segments / 2048 tasks max useful

    void* kargs[] = { (void*)&keys, (void*)&values, (void*)&queries,
                      (void*)&kcnt2, (void*)&klist2, (void*)&qcnt2,
                      (void*)&qpair, (void*)&outp };
    hipLaunchCooperativeKernel((void*)k_fused, dim3(grid), dim3(256),
                               kargs, 0, stream);
}

// Round 10
// 175.594 us; speedup vs baseline: 1.6892x; 1.6892x over previous
//
#include <hip/hip_runtime.h>
#include <math.h>

#define S_LEN 1024
#define EPS 1e-6f

typedef __attribute__((ext_vector_type(8)))  short bf16x8;
typedef __attribute__((ext_vector_type(16))) float float16v;

// Workspace layout (bytes):
//   kcnt2  : int  [32*32*64]      @ 0          (262144)  per (bh, seg, dim)
//   qcnt2  : int  [32*32*64]      @ 262144     (262144)
//   klist2 : ushort [2048*1024]   @ 524288     (4194304) [(bh,dim)][seg*32+pos]
//   qpair  : uint [2048*1024]     @ 4718592    (8388608) packed (w_hi22 | s_10)
// No memsets: counts fully overwritten every call; slots beyond count never
// read; d_out zeroed inside k_pre before k_main's atomics (verified R9).

__device__ __forceinline__ void wave_argmax(float& bv, int& bi) {
    #pragma unroll
    for (int off = 1; off < 64; off <<= 1) {
        float ov = __shfl_xor(bv, off, 64);
        int   oi = __shfl_xor(bi, off, 64);
        if (ov > bv || (ov == bv && oi < bi)) { bv = ov; bi = oi; }
    }
}

__device__ __forceinline__ unsigned short f2bf(float f) {
    unsigned int u = __float_as_uint(f);
    unsigned int r = (u + 0x7fffu + ((u >> 16) & 1u)) >> 16;
    return (unsigned short)r;
}

__device__ __forceinline__ bf16x8 pack8(float4 a, float4 b) {
    bf16x8 r;
    r[0] = (short)f2bf(a.x); r[1] = (short)f2bf(a.y);
    r[2] = (short)f2bf(a.z); r[3] = (short)f2bf(a.w);
    r[4] = (short)f2bf(b.x); r[5] = (short)f2bf(b.y);
    r[6] = (short)f2bf(b.z); r[7] = (short)f2bf(b.w);
    return r;
}

// 1024 blocks = (bh, seg); block handles 32 keys + 32 queries, owns 32-slot
// segment `seg` of every per-(bh,dim) list. LDS-histogram positions, no
// global atomics. Keys: 6-shuffle argmax (measured faster than rank count,
// R7 vs R8). Queries: exact duplicated-top-16 by rank counting. Also zeroes
// this block's d_out slice (replaces hipMemsetAsync).
__global__ __launch_bounds__(256) void k_pre(const float* __restrict__ keys,
                                             const float* __restrict__ queries,
                                             int* __restrict__ kcnt2,
                                             unsigned short* __restrict__ klist2,
                                             int* __restrict__ qcnt2,
                                             unsigned* __restrict__ qpair,
                                             float* __restrict__ out) {
    const int bh   = blockIdx.x >> 5;
    const int blk  = blockIdx.x & 31;          // segment id
    const int wv   = threadIdx.x >> 6;
    const int lane = threadIdx.x & 63;

    __shared__ int khist[64], qhist[64];
    if (threadIdx.x < 64) { khist[threadIdx.x] = 0; qhist[threadIdx.x] = 0; }
    __syncthreads();

    const int s0 = blk * 32 + wv * 8;
    float kv[8], qv[8];
    #pragma unroll
    for (int i = 0; i < 8; ++i) {              // all loads up-front (ILP)
        kv[i] = keys   [((size_t)bh * 1024 + s0 + i) * 64 + lane];
        qv[i] = queries[((size_t)bh * 1024 + s0 + i) * 64 + lane];
    }

    // zero d_out slice: 1024 blocks x 2048 floats = full 8.4 MB output
    {
        float4 zz = {0.f, 0.f, 0.f, 0.f};
        float4* po = (float4*)(out + (size_t)blockIdx.x * 2048);
        po[threadIdx.x] = zz; po[threadIdx.x + 256] = zz;
    }

    #pragma unroll
    for (int i = 0; i < 8; ++i) {              // keys: argmax -> scatter
        float bv = fabsf(kv[i]); int bi = lane;
        wave_argmax(bv, bi);
        if (lane == 0) {
            int pos = atomicAdd(&khist[bi], 1);
            klist2[((size_t)bh * 64 + bi) * 1024 + blk * 32 + pos] =
                (unsigned short)(s0 + i);
        }
    }

    #pragma unroll
    for (int i = 0; i < 8; ++i) {              // queries: rank counting
        unsigned ud = __float_as_uint(qv[i]) & 0x7fffffffu;
        int gt = 0, eq = 0, eql = 0;
        #pragma unroll
        for (int k = 0; k < 64; ++k) {
            unsigned ui = (unsigned)__builtin_amdgcn_readlane((int)ud, k);
            gt  += (ui > ud) ? 1 : 0;
            eq  += (ui == ud) ? 1 : 0;
            eql += (ui == ud && k < lane) ? 1 : 0;
        }
        int pos_low  = 2 * gt + eql;
        int pos_high = pos_low + eq;           // eq includes self
        int copies   = (pos_low < 16 ? 1 : 0) + (pos_high < 16 ? 1 : 0);
        float e  = expf(__uint_as_float(ud));
        float ce = (float)copies * e;
        #pragma unroll
        for (int off = 1; off < 64; off <<= 1) ce += __shfl_xor(ce, off, 64);
        if (pos_low < 16) {
            int pos = atomicAdd(&qhist[lane], 1);
            unsigned wb = __float_as_uint(e / ce) & 0xFFFFFC00u;
            qpair[((size_t)bh * 64 + lane) * 1024 + blk * 32 + pos] =
                wb | (unsigned)(s0 + i);
        }
    }
    __syncthreads();
    if (threadIdx.x < 64) {
        kcnt2[(bh * 32 + blk) * 64 + threadIdx.x] = khist[threadIdx.x];
        qcnt2[(bh * 32 + blk) * 64 + threadIdx.x] = qhist[threadIdx.x];
    }
}

// 2048 blocks = one per (bh, bank) -- NO chunk split: M built once per bank.
// LDS prefix tables (wave-0 shuffle scan, no VGPR arrays). Build M->bf16 + z
// fp32 (double-buffered staging, 1 barrier/iter). Query loop pipelined:
// {flush prev + stage cur} -> C -> {MFMA + epilogue} -> D, q_ent gathered in
// 256-entry chunks.
__global__ __launch_bounds__(256) void k_main(const float* __restrict__ keys,
                                              const float* __restrict__ values,
                                              const float* __restrict__ queries,
                                              const int* __restrict__ kcnt2,
                                              const unsigned short* __restrict__ klist2,
                                              const int* __restrict__ qcnt2,
                                              const unsigned* __restrict__ qpair,
                                              float* __restrict__ out) {
    const int g     = blockIdx.x;      // 0..2047
    const int bh    = g >> 6;
    const int bank  = g & 63;
    const int t     = threadIdx.x;
    const int lane  = t & 63;
    const int grp   = t >> 6;

    __shared__ alignas(16) unsigned short M_bf[64 * 64];   // 8 KB
    __shared__ alignas(16) unsigned short Q_bf[64 * 64];   // 8 KB
    __shared__ alignas(16) float Ou[64 * 66];              // 16.5 KB
    __shared__ unsigned short s_match[1024];               // 2 KB
    __shared__ unsigned q_ent[256];                        // 1 KB
    __shared__ int    koffs_s[33], qoffs_s[33];
    __shared__ float  z_s[64];
    __shared__ double den_s[64];
    __shared__ float  w_s[2][64];
    __shared__ int    sq_s[2][64];

    // wave 0: both 32-entry prefix scans (lanes 0-31 keys, 32-63 queries)
    if (t < 64) {
        int i = t & 31;
        int c = (t < 32) ? kcnt2[(bh * 32 + i) * 64 + bank]
                         : qcnt2[(bh * 32 + i) * 64 + bank];
        #pragma unroll
        for (int off = 1; off < 32; off <<= 1) {
            int o = __shfl(c, t - off, 64);    // guarded by i >= off
            if (i >= off) c += o;
        }
        if (t < 32) { if (i == 0) koffs_s[0] = 0; koffs_s[i + 1] = c; }
        else        { if (i == 0) qoffs_s[0] = 0; qoffs_s[i + 1] = c; }
    }
    __syncthreads();

    const int nm = koffs_s[32];
    const int nq = qoffs_s[32];
    if (nm == 0 || nq == 0) return;            // zero contribution, out pre-zeroed

    // gather key list via LDS-offs segment search (broadcast reads)
    for (int idx = t; idx < nm; idx += 256) {
        int seg = 0;
        #pragma unroll
        for (int i = 1; i < 32; ++i) if (idx >= koffs_s[i]) seg = i;
        s_match[idx] = klist2[(size_t)(bh * 64 + bank) * 1024 + seg * 32 +
                              (idx - koffs_s[seg])];
    }
    __syncthreads();

    // ---- build M[dv][dk] = sum v[dv]*k[dk], z[dk] = sum k[dk] (fp32) ----
    float acc[16];
    #pragma unroll
    for (int m = 0; m < 16; ++m) acc[m] = 0.f;
    float zacc = 0.f;
    const float* kb = keys   + (size_t)bh * S_LEN * 64;
    const float* vb = values + (size_t)bh * S_LEN * 64;
    for (int base = 0, it = 0; base < nm; base += 8, ++it) {
        float* kst = Ou + (it & 1) * 1024;     // [8][64] ping-pong
        float* vst = kst + 512;
        #pragma unroll
        for (int rr = 0; rr < 2; ++rr) {
            int row = grp + rr * 4;
            if (base + row < nm) {
                int s = s_match[base + row];
                kst[row * 64 + lane] = kb[(size_t)s * 64 + lane];
                vst[row * 64 + lane] = vb[(size_t)s * 64 + lane];
            }
        }
        __syncthreads();               // staging visible (1 barrier/iter)
        int lim = min(8, nm - base);
        for (int jj = 0; jj < lim; ++jj) {
            float kv = kst[jj * 64 + lane];            // dk = lane
            #pragma unroll
            for (int m = 0; m < 16; ++m)               // dv = grp*16+m
                acc[m] += vst[jj * 64 + grp * 16 + m] * kv;
        }
        if (t < 64)
            for (int jj = 0; jj < lim; ++jj) zacc += kst[jj * 64 + t];
    }
    // write M as bf16, row-major [dv][dk], 16B-chunk XOR swizzle
    #pragma unroll
    for (int m = 0; m < 16; ++m) {
        int dv = grp * 16 + m;
        M_bf[dv * 64 + (((lane >> 3) ^ (dv & 7)) << 3) + (lane & 7)] = f2bf(acc[m]);
    }
    if (t < 64) z_s[t] = zacc;
    // visibility: first q_ent-gather barrier below covers M_bf/z_s

    // ---- query loop: pipelined, 2 barriers/batch + 1 per 256-chunk ----
    const float* qb = queries + (size_t)bh * S_LEN * 64;
    float*       ob = out     + (size_t)bh * S_LEN * 64;
    const int dvh = grp >> 1, jh = grp & 1;            // wave's 32x32 tile

    int prev_nb = 0;
    for (int qbase = 0, batch = 0; qbase < nq; qbase += 64, ++batch) {
        const int nb  = min(64, nq - qbase);
        const int cur = batch & 1;

        if ((qbase & 255) == 0) {      // gather next 256 entries into q_ent
            if (qbase + t < nq) {
                int jg = qbase + t;
                int seg = 0;
                #pragma unroll
                for (int i = 1; i < 32; ++i) if (jg >= qoffs_s[i]) seg = i;
                q_ent[t] = qpair[(size_t)(bh * 64 + bank) * 1024 + seg * 32 +
                                 (jg - qoffs_s[seg])];
            }
            __syncthreads();           // q_ent (and M_bf/z_s on first iter)
        }

        // phase S: flush previous batch (reads Ou + sq_s[1-cur]) ...
        if (batch > 0) {
            #pragma unroll
            for (int jj = 0; jj < 16; ++jj) {
                int j = grp * 16 + jj;
                if (j < prev_nb) {
                    float v = Ou[j * 66 + lane];
                    unsafeAtomicAdd(&ob[(size_t)sq_s[1 - cur][j] * 64 + lane], v);
                }
            }
        }
        // ... and stage current batch: thread -> (j = t>>2, slice c4 = t&3)
        {
            int j = t >> 2, c4 = t & 3;
            bf16x8 p0 = {}, p1 = {};
            double d = 0.0;
            if (j < nb) {
                unsigned e = q_ent[(qbase & 255) + j];
                int s = (int)(e & 1023u);
                if ((t & 3) == 0) {
                    sq_s[cur][j] = s;
                    w_s[cur][j]  = __uint_as_float(e & 0xFFFFFC00u);
                }
                const float4* src = (const float4*)(qb + (size_t)s * 64 + c4 * 16);
                float4 f0 = src[0], f1 = src[1], f2 = src[2], f3 = src[3];
                p0 = pack8(f0, f1);
                p1 = pack8(f2, f3);
                const float4* zz4 = (const float4*)&z_s[c4 * 16];
                float4 z0 = zz4[0], z1 = zz4[1], z2 = zz4[2], z3 = zz4[3];
                d  = (double)z0.x * f0.x + (double)z0.y * f0.y + (double)z0.z * f0.z + (double)z0.w * f0.w;
                d += (double)z1.x * f1.x + (double)z1.y * f1.y + (double)z1.z * f1.z + (double)z1.w * f1.w;
                d += (double)z2.x * f2.x + (double)z2.y * f2.y + (double)z2.z * f2.z + (double)z2.w * f2.w;
                d += (double)z3.x * f3.x + (double)z3.y * f3.y + (double)z3.z * f3.z + (double)z3.w * f3.w;
            }
            int c0 = c4 * 2;
            *(bf16x8*)&Q_bf[j * 64 + ((c0 ^ (j & 7)) << 3)]       = p0;
            *(bf16x8*)&Q_bf[j * 64 + (((c0 + 1) ^ (j & 7)) << 3)] = p1;
            d += __shfl_xor(d, 1, 64);
            d += __shfl_xor(d, 2, 64);
            if ((t & 3) == 0) den_s[j] = d;
        }
        __syncthreads();               // (C) staged; prev Ou reads complete

        // MFMA: O[dv][j] = sum_dk M[dv][dk] * Q[j][dk]
        float16v C;
        #pragma unroll
        for (int i = 0; i < 16; ++i) C[i] = 0.f;
        const int am = dvh * 32 + (lane & 31);
        const int bn = jh  * 32 + (lane & 31);
        #pragma unroll
        for (int ks = 0; ks < 4; ++ks) {
            int ch = ks * 2 + (lane >> 5);
            bf16x8 af = *(const bf16x8*)&M_bf[am * 64 + ((ch ^ (am & 7)) << 3)];
            bf16x8 bf = *(const bf16x8*)&Q_bf[bn * 64 + ((ch ^ (bn & 7)) << 3)];
            C = __builtin_amdgcn_mfma_f32_32x32x16_bf16(af, bf, C, 0, 0, 0);
        }
        // epilogue: scale by w/den, write O[j][dv] (stride 66)
        {
            double den = den_s[bn];
            float  w   = w_s[cur][bn];
            float rinv = (float)((double)w / (den + (double)EPS));
            #pragma unroll
            for (int r = 0; r < 16; ++r) {
                int dv = dvh * 32 + (r & 3) + 8 * (r >> 2) + 4 * (lane >> 5);
                Ou[bn * 66 + dv] = C[r] * rinv;
            }
        }
        __syncthreads();               // (D) O ready; Q_bf reads complete
        prev_nb = nb;
    }
    // final flush
    {
        const int cur = (((nq + 63) >> 6) - 1) & 1;    // parity of last batch
        #pragma unroll
        for (int jj = 0; jj < 16; ++jj) {
            int j = grp * 16 + jj;
            if (j < prev_nb) {
                float v = Ou[j * 66 + lane];
                unsafeAtomicAdd(&ob[(size_t)sq_s[cur][j] * 64 + lane], v);
            }
        }
    }
}

extern "C" void kernel_launch(void* const* d_in, const int* in_sizes, int n_in,
                              void* d_out, int out_size, void* d_ws, size_t ws_size,
                              hipStream_t stream) {
    const float* keys    = (const float*)d_in[0];
    const float* values  = (const float*)d_in[1];
    const float* queries = (const float*)d_in[2];
    char* ws = (char*)d_ws;
    int*            kcnt2  = (int*)(ws);
    int*            qcnt2  = (int*)(ws + 262144);
    unsigned short* klist2 = (unsigned short*)(ws + 524288);
    unsigned*       qpair  = (unsigned*)(ws + 4718592);

    k_pre <<<1024, 256, 0, stream>>>(keys, queries, kcnt2, klist2, qcnt2, qpair,
                                     (float*)d_out);
    k_main<<<2048, 256, 0, stream>>>(keys, values, queries, kcnt2, klist2, qcnt2, qpair,
                                     (float*)d_out);
}

// Round 11
// 160.792 us; speedup vs baseline: 1.8447x; 1.0921x over previous
//
#include <hip/hip_runtime.h>
#include <math.h>

#define S_LEN 1024
#define EPS 1e-6f

typedef __attribute__((ext_vector_type(8)))  short bf16x8;
typedef __attribute__((ext_vector_type(4)))  short bf16x4;
typedef __attribute__((ext_vector_type(16))) float float16v;

// Workspace layout (bytes):
//   kcnt2  : int  [32*32*64]      @ 0          (262144)  per (bh, seg, dim)
//   qcnt2  : int  [32*32*64]      @ 262144     (262144)
//   klist2 : ushort [2048*1024]   @ 524288     (4194304) [(bh,dim)][seg*32+pos]
//   qpair  : uint [2048*1024]     @ 4718592    (8388608) packed (w_hi22 | s_10)
// No memsets: counts fully overwritten every call; slots beyond count never
// read; d_out zeroed inside k_pre before k_main's atomics (verified R9/R10).

__device__ __forceinline__ void wave_argmax(float& bv, int& bi) {
    #pragma unroll
    for (int off = 1; off < 64; off <<= 1) {
        float ov = __shfl_xor(bv, off, 64);
        int   oi = __shfl_xor(bi, off, 64);
        if (ov > bv || (ov == bv && oi < bi)) { bv = ov; bi = oi; }
    }
}

__device__ __forceinline__ unsigned short f2bf(float f) {
    unsigned int u = __float_as_uint(f);
    unsigned int r = (u + 0x7fffu + ((u >> 16) & 1u)) >> 16;
    return (unsigned short)r;
}

__device__ __forceinline__ bf16x8 pack8(float4 a, float4 b) {
    bf16x8 r;
    r[0] = (short)f2bf(a.x); r[1] = (short)f2bf(a.y);
    r[2] = (short)f2bf(a.z); r[3] = (short)f2bf(a.w);
    r[4] = (short)f2bf(b.x); r[5] = (short)f2bf(b.y);
    r[6] = (short)f2bf(b.z); r[7] = (short)f2bf(b.w);
    return r;
}

// 1024 blocks = (bh, seg); block handles 32 keys + 32 queries, owns 32-slot
// segment `seg` of every per-(bh,dim) list. LDS-histogram positions, no
// global atomics. Keys: 6-shuffle argmax. Queries: rank counting with a
// tie-free fast path (sum(gt) == 2016 <=> all 64 |q| distinct -> pos_low=2*gt,
// copies = 2*(gt<8)); exact slow path on the rare tie rows. Also zeroes this
// block's d_out slice (replaces hipMemsetAsync).
__global__ __launch_bounds__(256) void k_pre(const float* __restrict__ keys,
                                             const float* __restrict__ queries,
                                             int* __restrict__ kcnt2,
                                             unsigned short* __restrict__ klist2,
                                             int* __restrict__ qcnt2,
                                             unsigned* __restrict__ qpair,
                                             float* __restrict__ out) {
    const int bh   = blockIdx.x >> 5;
    const int blk  = blockIdx.x & 31;          // segment id
    const int wv   = threadIdx.x >> 6;
    const int lane = threadIdx.x & 63;

    __shared__ int khist[64], qhist[64];
    if (threadIdx.x < 64) { khist[threadIdx.x] = 0; qhist[threadIdx.x] = 0; }
    __syncthreads();

    const int s0 = blk * 32 + wv * 8;
    float kv[8], qv[8];
    #pragma unroll
    for (int i = 0; i < 8; ++i) {              // all loads up-front (ILP)
        kv[i] = keys   [((size_t)bh * 1024 + s0 + i) * 64 + lane];
        qv[i] = queries[((size_t)bh * 1024 + s0 + i) * 64 + lane];
    }

    // zero d_out slice: 1024 blocks x 2048 floats = full output
    {
        float4 zz = {0.f, 0.f, 0.f, 0.f};
        float4* po = (float4*)(out + (size_t)blockIdx.x * 2048);
        po[threadIdx.x] = zz; po[threadIdx.x + 256] = zz;
    }

    #pragma unroll
    for (int i = 0; i < 8; ++i) {              // keys: argmax -> scatter
        float bv = fabsf(kv[i]); int bi = lane;
        wave_argmax(bv, bi);
        if (lane == 0) {
            int pos = atomicAdd(&khist[bi], 1);
            klist2[((size_t)bh * 64 + bi) * 1024 + blk * 32 + pos] =
                (unsigned short)(s0 + i);
        }
    }

    #pragma unroll
    for (int i = 0; i < 8; ++i) {              // queries
        unsigned ud = __float_as_uint(qv[i]) & 0x7fffffffu;
        int gt = 0;
        #pragma unroll
        for (int k = 0; k < 64; ++k) {
            unsigned ui = (unsigned)__builtin_amdgcn_readlane((int)ud, k);
            gt += (ui > ud) ? 1 : 0;
        }
        int S = gt;                            // permutation check for ties
        #pragma unroll
        for (int off = 1; off < 64; off <<= 1) S += __shfl_xor(S, off, 64);
        float e = expf(__uint_as_float(ud));
        int copies, contrib;
        if (S == 2016) {                       // no ties (wave-uniform branch)
            contrib = (gt < 8);
            copies  = contrib ? 2 : 0;
        } else {                               // exact tie handling (rare)
            int eq = 0, eql = 0;
            #pragma unroll
            for (int k = 0; k < 64; ++k) {
                unsigned ui = (unsigned)__builtin_amdgcn_readlane((int)ud, k);
                eq  += (ui == ud) ? 1 : 0;
                eql += (ui == ud && k < lane) ? 1 : 0;
            }
            int pos_low  = 2 * gt + eql;
            int pos_high = pos_low + eq;       // eq includes self
            copies  = (pos_low < 16 ? 1 : 0) + (pos_high < 16 ? 1 : 0);
            contrib = (pos_low < 16);
        }
        float ce = (float)copies * e;
        #pragma unroll
        for (int off = 1; off < 64; off <<= 1) ce += __shfl_xor(ce, off, 64);
        if (contrib) {
            int pos = atomicAdd(&qhist[lane], 1);
            unsigned wb = __float_as_uint(e / ce) & 0xFFFFFC00u;
            qpair[((size_t)bh * 64 + lane) * 1024 + blk * 32 + pos] =
                wb | (unsigned)(s0 + i);
        }
    }
    __syncthreads();
    if (threadIdx.x < 64) {
        kcnt2[(bh * 32 + blk) * 64 + threadIdx.x] = khist[threadIdx.x];
        qcnt2[(bh * 32 + blk) * 64 + threadIdx.x] = qhist[threadIdx.x];
    }
}

// 2048 blocks = one per (bh, bank). LDS trimmed to ~28.7 KB -> 5 blocks/CU:
// O-transpose buffer in bf16 (packed ds_write_b64), key list gathered in
// 256-entry chunks. Build M->bf16 + z fp32 (double-buffered staging, 1
// barrier/iter). Query loop pipelined: {flush prev + stage cur} -> C ->
// {MFMA + epilogue} -> D; q_ent gathered in 256-entry chunks.
__global__ __launch_bounds__(256) void k_main(const float* __restrict__ keys,
                                              const float* __restrict__ values,
                                              const float* __restrict__ queries,
                                              const int* __restrict__ kcnt2,
                                              const unsigned short* __restrict__ klist2,
                                              const int* __restrict__ qcnt2,
                                              const unsigned* __restrict__ qpair,
                                              float* __restrict__ out) {
    const int g     = blockIdx.x;      // 0..2047
    const int bh    = g >> 6;
    const int bank  = g & 63;
    const int t     = threadIdx.x;
    const int lane  = t & 63;
    const int grp   = t >> 6;

    __shared__ alignas(16) unsigned short M_bf[64 * 64];   // 8 KB
    __shared__ alignas(16) unsigned short Q_bf[64 * 64];   // 8 KB
    __shared__ alignas(16) unsigned short Ou_bf[64 * 68];  // 8.7 KB (O^T bf16 / build staging)
    __shared__ unsigned short s_match[256];                // 0.5 KB (chunked)
    __shared__ unsigned q_ent[256];                        // 1 KB (chunked)
    __shared__ int    koffs_s[33], qoffs_s[33];
    __shared__ float  z_s[64];
    __shared__ double den_s[64];
    __shared__ float  w_s[2][64];
    __shared__ int    sq_s[2][64];
    // total ~28.7 KB -> 5 blocks/CU

    // wave 0: both 32-entry prefix scans (lanes 0-31 keys, 32-63 queries)
    if (t < 64) {
        int i = t & 31;
        int c = (t < 32) ? kcnt2[(bh * 32 + i) * 64 + bank]
                         : qcnt2[(bh * 32 + i) * 64 + bank];
        #pragma unroll
        for (int off = 1; off < 32; off <<= 1) {
            int o = __shfl(c, t - off, 64);    // guarded by i >= off
            if (i >= off) c += o;
        }
        if (t < 32) { if (i == 0) koffs_s[0] = 0; koffs_s[i + 1] = c; }
        else        { if (i == 0) qoffs_s[0] = 0; qoffs_s[i + 1] = c; }
    }
    __syncthreads();

    const int nm = koffs_s[32];
    const int nq = qoffs_s[32];
    if (nm == 0 || nq == 0) return;            // zero contribution, out pre-zeroed

    // ---- build M[dv][dk] = sum v[dv]*k[dk], z[dk] = sum k[dk] (fp32) ----
    float acc[16];
    #pragma unroll
    for (int m = 0; m < 16; ++m) acc[m] = 0.f;
    float zacc = 0.f;
    const float* kb = keys   + (size_t)bh * S_LEN * 64;
    const float* vb = values + (size_t)bh * S_LEN * 64;
    int it = 0;
    for (int cb = 0; cb < nm; cb += 256) {     // 256-key chunks (1 chunk typical)
        const int cn = min(256, nm - cb);
        __syncthreads();                       // prev chunk's s_match reads done
        if (t < cn) {                          // gather chunk via segment search
            int idx = cb + t;
            int seg = 0;
            #pragma unroll
            for (int i = 1; i < 32; ++i) if (idx >= koffs_s[i]) seg = i;
            s_match[t] = klist2[(size_t)(bh * 64 + bank) * 1024 + seg * 32 +
                                (idx - koffs_s[seg])];
        }
        __syncthreads();
        for (int base = 0; base < cn; base += 8, ++it) {
            float* kst = (float*)Ou_bf + (it & 1) * 1024;  // [8][64] ping-pong
            float* vst = kst + 512;
            #pragma unroll
            for (int rr = 0; rr < 2; ++rr) {
                int row = grp + rr * 4;
                if (base + row < cn) {
                    int s = s_match[base + row];
                    kst[row * 64 + lane] = kb[(size_t)s * 64 + lane];
                    vst[row * 64 + lane] = vb[(size_t)s * 64 + lane];
                }
            }
            __syncthreads();           // staging visible (1 barrier/iter)
            int lim = min(8, cn - base);
            for (int jj = 0; jj < lim; ++jj) {
                float kv = kst[jj * 64 + lane];        // dk = lane
                #pragma unroll
                for (int m = 0; m < 16; ++m)           // dv = grp*16+m
                    acc[m] += vst[jj * 64 + grp * 16 + m] * kv;
            }
            if (t < 64)
                for (int jj = 0; jj < lim; ++jj) zacc += kst[jj * 64 + t];
        }
    }
    // write M as bf16, row-major [dv][dk], 16B-chunk XOR swizzle
    #pragma unroll
    for (int m = 0; m < 16; ++m) {
        int dv = grp * 16 + m;
        M_bf[dv * 64 + (((lane >> 3) ^ (dv & 7)) << 3) + (lane & 7)] = f2bf(acc[m]);
    }
    if (t < 64) z_s[t] = zacc;
    // visibility: first q_ent-gather barrier below covers M_bf/z_s

    // ---- query loop: pipelined, 2 barriers/batch + 1 per 256-chunk ----
    const float* qb = queries + (size_t)bh * S_LEN * 64;
    float*       ob = out     + (size_t)bh * S_LEN * 64;
    const int dvh = grp >> 1, jh = grp & 1;            // wave's 32x32 tile
    const int hi  = lane >> 5;

    int prev_nb = 0;
    for (int qbase = 0, batch = 0; qbase < nq; qbase += 64, ++batch) {
        const int nb  = min(64, nq - qbase);
        const int cur = batch & 1;

        if ((qbase & 255) == 0) {      // gather next 256 entries into q_ent
            if (qbase + t < nq) {
                int jg = qbase + t;
                int seg = 0;
                #pragma unroll
                for (int i = 1; i < 32; ++i) if (jg >= qoffs_s[i]) seg = i;
                q_ent[t] = qpair[(size_t)(bh * 64 + bank) * 1024 + seg * 32 +
                                 (jg - qoffs_s[seg])];
            }
            __syncthreads();           // q_ent (and M_bf/z_s on first iter)
        }

        // phase S: flush previous batch (reads Ou_bf + sq_s[1-cur]) ...
        if (batch > 0) {
            #pragma unroll
            for (int jj = 0; jj < 16; ++jj) {
                int j = grp * 16 + jj;
                if (j < prev_nb) {
                    float v = __uint_as_float((unsigned)Ou_bf[j * 68 + lane] << 16);
                    unsafeAtomicAdd(&ob[(size_t)sq_s[1 - cur][j] * 64 + lane], v);
                }
            }
        }
        // ... and stage current batch: thread -> (j = t>>2, slice c4 = t&3)
        {
            int j = t >> 2, c4 = t & 3;
            bf16x8 p0 = {}, p1 = {};
            double d = 0.0;
            if (j < nb) {
                unsigned e = q_ent[(qbase & 255) + j];
                int s = (int)(e & 1023u);
                if ((t & 3) == 0) {
                    sq_s[cur][j] = s;
                    w_s[cur][j]  = __uint_as_float(e & 0xFFFFFC00u);
                }
                const float4* src = (const float4*)(qb + (size_t)s * 64 + c4 * 16);
                float4 f0 = src[0], f1 = src[1], f2 = src[2], f3 = src[3];
                p0 = pack8(f0, f1);
                p1 = pack8(f2, f3);
                const float4* zz4 = (const float4*)&z_s[c4 * 16];
                float4 z0 = zz4[0], z1 = zz4[1], z2 = zz4[2], z3 = zz4[3];
                d  = (double)z0.x * f0.x + (double)z0.y * f0.y + (double)z0.z * f0.z + (double)z0.w * f0.w;
                d += (double)z1.x * f1.x + (double)z1.y * f1.y + (double)z1.z * f1.z + (double)z1.w * f1.w;
                d += (double)z2.x * f2.x + (double)z2.y * f2.y + (double)z2.z * f2.z + (double)z2.w * f2.w;
                d += (double)z3.x * f3.x + (double)z3.y * f3.y + (double)z3.z * f3.z + (double)z3.w * f3.w;
            }
            int c0 = c4 * 2;
            *(bf16x8*)&Q_bf[j * 64 + ((c0 ^ (j & 7)) << 3)]       = p0;
            *(bf16x8*)&Q_bf[j * 64 + (((c0 + 1) ^ (j & 7)) << 3)] = p1;
            d += __shfl_xor(d, 1, 64);
            d += __shfl_xor(d, 2, 64);
            if ((t & 3) == 0) den_s[j] = d;
        }
        __syncthreads();               // (C) staged; prev Ou_bf reads complete

        // MFMA: O[dv][j] = sum_dk M[dv][dk] * Q[j][dk]
        float16v C;
        #pragma unroll
        for (int i = 0; i < 16; ++i) C[i] = 0.f;
        const int am = dvh * 32 + (lane & 31);
        const int bn = jh  * 32 + (lane & 31);
        #pragma unroll
        for (int ks = 0; ks < 4; ++ks) {
            int ch = ks * 2 + hi;
            bf16x8 af = *(const bf16x8*)&M_bf[am * 64 + ((ch ^ (am & 7)) << 3)];
            bf16x8 bf = *(const bf16x8*)&Q_bf[bn * 64 + ((ch ^ (bn & 7)) << 3)];
            C = __builtin_amdgcn_mfma_f32_32x32x16_bf16(af, bf, C, 0, 0, 0);
        }
        // epilogue: scale by w/den, write O^T[j=bn][dv] as bf16 (b64-packed:
        // rows r=4rq..4rq+3 give consecutive dv = dvh*32 + 8rq + 4*hi + 0..3)
        {
            double den = den_s[bn];
            float  w   = w_s[cur][bn];
            float rinv = (float)((double)w / (den + (double)EPS));
            #pragma unroll
            for (int rq = 0; rq < 4; ++rq) {
                bf16x4 pk;
                pk[0] = (short)f2bf(C[rq * 4 + 0] * rinv);
                pk[1] = (short)f2bf(C[rq * 4 + 1] * rinv);
                pk[2] = (short)f2bf(C[rq * 4 + 2] * rinv);
                pk[3] = (short)f2bf(C[rq * 4 + 3] * rinv);
                *(bf16x4*)&Ou_bf[bn * 68 + dvh * 32 + rq * 8 + hi * 4] = pk;
            }
        }
        __syncthreads();               // (D) O ready; Q_bf reads complete
        prev_nb = nb;
    }
    // final flush
    {
        const int cur = (((nq + 63) >> 6) - 1) & 1;    // parity of last batch
        #pragma unroll
        for (int jj = 0; jj < 16; ++jj) {
            int j = grp * 16 + jj;
            if (j < prev_nb) {
                float v = __uint_as_float((unsigned)Ou_bf[j * 68 + lane] << 16);
                unsafeAtomicAdd(&ob[(size_t)sq_s[cur][j] * 64 + lane], v);
            }
        }
    }
}

extern "C" void kernel_launch(void* const* d_in, const int* in_sizes, int n_in,
                              void* d_out, int out_size, void* d_ws, size_t ws_size,
                              hipStream_t stream) {
    const float* keys    = (const float*)d_in[0];
    const float* values  = (const float*)d_in[1];
    const float* queries = (const float*)d_in[2];
    char* ws = (char*)d_ws;
    int*            kcnt2  = (int*)(ws);
    int*            qcnt2  = (int*)(ws + 262144);
    unsigned short* klist2 = (unsigned short*)(ws + 524288);
    unsigned*       qpair  = (unsigned*)(ws + 4718592);

    k_pre <<<1024, 256, 0, stream>>>(keys, queries, kcnt2, klist2, qcnt2, qpair,
                                     (float*)d_out);
    k_main<<<2048, 256, 0, stream>>>(keys, values, queries, kcnt2, klist2, qcnt2, qpair,
                                     (float*)d_out);
}